// Round 9
// baseline (234.314 us; speedup 1.0000x reference)
//
#include <hip/hip_runtime.h>
#include <math.h>

// out[b, l, d] = x[b, l, d] + pe[l, d]
// pe[l, 0:128]   : interleaved sin/cos of row * freq_m   (m = 0..63)
// pe[l, 128:256] : interleaved sin/cos of col * freq_m
// freq_m = exp(-m * ln(10000)/64),  l = row * w + col,  d_model = 256
//
// Structure: PERSISTENT GRID (2048 blocks x 256 threads) + grid-stride loop
// over the linear float4 index (Guideline 11). Identical per-element math to
// the verified round-5 kernel; the only change vs r5 is the grid shape —
// isolating block-launch churn as the last untested limiter (32768 one-shot
// blocks, 1 ld+st per thread, vs a copy-bench-style persistent grid).
// stride = 2048*256 == 0 (mod 64)  =>  j (channel index) is loop-invariant,
// so the two __expf hoist out of the loop.

typedef float f32x4 __attribute__((ext_vector_type(4)));

__global__ __launch_bounds__(256) void pe_add_kernel(
    const float* __restrict__ x,
    const int* __restrict__ hp,
    const int* __restrict__ wp,
    float* __restrict__ out,
    unsigned int n4)   // total number of float4 elements
{
    const unsigned int ww = (unsigned int)(*wp);
    const unsigned int hh = (unsigned int)(*hp);
    const unsigned int L  = hh * ww;

    const bool pow2 = ((ww & (ww - 1u)) | (L & (L - 1u))) == 0u;
    const unsigned int wshift = (unsigned int)__builtin_ctz(ww);

    const unsigned int stride = gridDim.x * blockDim.x;   // multiple of 64
    const unsigned int start  = blockIdx.x * blockDim.x + threadIdx.x;

    // channel-dependent factors: loop-invariant (stride % 64 == 0)
    const unsigned int j  = start & 63u;
    const unsigned int d0 = j << 2;
    const unsigned int m0 = (d0 & 127u) >> 1;
    const float cstep = 0.14391156831212787f;  // ln(10000)/64
    const float f0 = __expf(-(float)m0 * cstep);
    const float f1 = __expf(-(float)(m0 + 1u) * cstep);
    const bool rowhalf = (d0 < 128u);

    const f32x4* __restrict__ xp = reinterpret_cast<const f32x4*>(x);
    f32x4* __restrict__       op = reinterpret_cast<f32x4*>(out);

    for (unsigned int idx = start; idx < n4; idx += stride) {
        const unsigned int t = idx >> 6;       // b * L + l
        unsigned int l, row, col;
        if (pow2) { l = t & (L - 1u); row = l >> wshift; col = l & (ww - 1u); }
        else      { l = t % L;        row = l / ww;      col = l - row * ww; }
        const float pos = (float)(rowhalf ? row : col);

        float s0, c0, s1, c1;
        __sincosf(pos * f0, &s0, &c0);
        __sincosf(pos * f1, &s1, &c1);

        const f32x4 pe = { s0, c0, s1, c1 };
        op[idx] = xp[idx] + pe;
    }
}

extern "C" void kernel_launch(void* const* d_in, const int* in_sizes, int n_in,
                              void* d_out, int out_size, void* d_ws, size_t ws_size,
                              hipStream_t stream) {
    const float* x = (const float*)d_in[0];
    const int* hp  = (const int*)d_in[1];
    const int* wp  = (const int*)d_in[2];
    float* out     = (float*)d_out;

    // out_size is in float elements -> float4 count = /4 (verified)
    const unsigned int n4 = (unsigned int)(out_size / 4);

    unsigned int blocks = (n4 + 255u) / 256u;
    if (blocks > 2048u) blocks = 2048u;       // persistent grid, grid-stride
    pe_add_kernel<<<blocks, 256, 0, stream>>>(x, hp, wp, out, n4);
}